// Round 2
// baseline (199.259 us; speedup 1.0000x reference)
//
#include <hip/hip_runtime.h>
#include <hip/hip_bf16.h>

typedef __bf16 bf16x8 __attribute__((ext_vector_type(8)));
typedef float  f32x4  __attribute__((ext_vector_type(4)));

#define V_TOTAL   32768
#define VBLK      64
#define NTHREADS  256
#define H1_STRIDE 528   // 256 bf16 (512B) + 16B pad -> conflict-free-ish ds_read_b128
#define A_STRIDE  80    // 32 bf16 (64B) + 16B pad
#define LDS_H1 (VBLK * H1_STRIDE)   // 33792 B
#define LDS_A  (256 * A_STRIDE)     // 20480 B

// ---- prep: w2 fp32 -> bf16 (RNE) into workspace ----
__global__ void w2_to_bf16(const float* __restrict__ w2, __bf16* __restrict__ w2b) {
    int i = blockIdx.x * 256 + threadIdx.x;   // grid sized exactly: 8*256*256
    w2b[i] = (__bf16)w2[i];
}

__global__ __launch_bounds__(NTHREADS, 2) void fused_mlp(
    const float* __restrict__ x,  const int* __restrict__ obj,
    const float* __restrict__ w1, const float* __restrict__ b1,
    const float* __restrict__ b2, const float* __restrict__ w3,
    const float* __restrict__ b3, const __bf16* __restrict__ w2b,
    float* __restrict__ out)
{
    __shared__ __align__(16) char lds[LDS_H1 + LDS_A];   // 54272 B < 64 KB static
    char* h1t   = lds;            // [VBLK][H1_STRIDE]: h1 transposed, bf16, pos-major
    char* atile = lds + LDS_H1;   // [256][A_STRIDE]: W2 K-tile, bf16
    float* w1s = (float*)atile;           // union: layer-1 weights live before atile
    float* b1s = (float*)(atile + 6144);

    const int t   = threadIdx.x;
    const int blk = blockIdx.x;
    const int b   = blk >> 9;            // 512 v-chunks per sample
    const int v0  = (blk & 511) * VBLK;
    const int e   = obj[b];

    for (int i = t; i < 256 * 6; i += NTHREADS) w1s[i] = w1[e * 1536 + i];
    if (t < 256) b1s[t] = b1[e * 256 + t];
    __syncthreads();

    // ---- layer 1 (fp32 VALU): h1t[n][m] = relu(W1 x + b1), stored bf16 ----
    {
        const int n  = t & 63;     // position within chunk (lane id)
        const int mg = t >> 6;     // wave id -> 64 hidden rows each
        float xr[6];
        #pragma unroll
        for (int i = 0; i < 6; ++i)
            xr[i] = x[(size_t)b * 6 * V_TOTAL + (size_t)i * V_TOTAL + v0 + n];
        char* drow = h1t + n * H1_STRIDE;
        #pragma unroll
        for (int q = 0; q < 8; ++q) {
            int m8 = mg * 8 + q;
            bf16x8 pack;
            #pragma unroll
            for (int j = 0; j < 8; ++j) {
                int m = m8 * 8 + j;
                float a = b1s[m];
                #pragma unroll
                for (int i = 0; i < 6; ++i) a = fmaf(w1s[m * 6 + i], xr[i], a);
                pack[j] = (__bf16)fmaxf(a, 0.f);
            }
            *(bf16x8*)(drow + m8 * 16) = pack;   // 16B aligned (528 = 33*16)
        }
    }

    // ---- layer 2 (MFMA 16x16x32 bf16): M=256, K=256, wave owns N=16 cols ----
    const int lane = t & 63;
    const int wv   = t >> 6;
    const int llo  = lane & 15;
    const int lhi  = lane >> 4;
    const int n0   = wv * 16;

    f32x4 acc[16];
    #pragma unroll
    for (int mt = 0; mt < 16; ++mt)   // init with bias b2 (row-broadcast)
        acc[mt] = *(const f32x4*)(b2 + e * 256 + mt * 16 + lhi * 4);

    const __bf16* w2e = w2b + (size_t)e * 65536;
    const char*   brow = h1t + (n0 + llo) * H1_STRIDE;   // B-frag row: col = n0+llo

    for (int k0 = 0; k0 < 256; k0 += 32) {
        __syncthreads();                       // prev tile's A-frag reads done
        #pragma unroll
        for (int i = 0; i < 4; ++i) {          // stage W2[m][k0..k0+32) -> atile
            int c = t + i * NTHREADS;          // 1024 chunks of 16B
            int m = c >> 2, slot = c & 3;
            bf16x8 v = *(const bf16x8*)(w2e + m * 256 + k0 + slot * 8);
            *(bf16x8*)(atile + m * A_STRIDE + slot * 16) = v;
        }
        __syncthreads();
        // B fragment: B[k][col], col = n0+llo, k = k0 + lhi*8 + j
        bf16x8 bfrag = *(const bf16x8*)(brow + (k0 + lhi * 8) * 2);
        #pragma unroll
        for (int mt = 0; mt < 16; ++mt) {
            // A fragment: A[m][k], m = mt*16+llo, k = k0 + lhi*8 + j
            const bf16x8 afrag =
                *(const bf16x8*)(atile + (mt * 16 + llo) * A_STRIDE + lhi * 16);
            acc[mt] = __builtin_amdgcn_mfma_f32_16x16x32_bf16(afrag, bfrag, acc[mt], 0, 0, 0);
        }
    }

    // ---- layer 3 (fp32): out = w3 . relu(h2) + b3, wave-local reduction ----
    float partial = 0.f;
    #pragma unroll
    for (int mt = 0; mt < 16; ++mt) {
        f32x4 wv4 = *(const f32x4*)(w3 + e * 256 + mt * 16 + lhi * 4);
        #pragma unroll
        for (int r = 0; r < 4; ++r)
            partial = fmaf(wv4[r], fmaxf(acc[mt][r], 0.f), partial);
    }
    partial += __shfl_xor(partial, 16, 64);
    partial += __shfl_xor(partial, 32, 64);
    if (lane < 16)
        out[(size_t)b * V_TOTAL + v0 + n0 + llo] = partial + b3[e];
}

extern "C" void kernel_launch(void* const* d_in, const int* in_sizes, int n_in,
                              void* d_out, int out_size, void* d_ws, size_t ws_size,
                              hipStream_t stream) {
    const float* x   = (const float*)d_in[0];
    const int*   obj = (const int*)d_in[1];
    const float* w1  = (const float*)d_in[2];
    const float* b1  = (const float*)d_in[3];
    const float* w2  = (const float*)d_in[4];
    const float* b2  = (const float*)d_in[5];
    const float* w3  = (const float*)d_in[6];
    const float* b3  = (const float*)d_in[7];
    float*  out = (float*)d_out;
    __bf16* w2b = (__bf16*)d_ws;   // 8*256*256 bf16 = 1 MB

    w2_to_bf16<<<2048, 256, 0, stream>>>(w2, w2b);          // 524288 elems
    fused_mlp<<<8192, NTHREADS, 0, stream>>>(x, obj, w1, b1, b2, w3, b3, w2b, out);
}

// Round 4
// 154.574 us; speedup vs baseline: 1.2891x; 1.2891x over previous
//
#include <hip/hip_runtime.h>
#include <hip/hip_bf16.h>

typedef __bf16 bf16x8 __attribute__((ext_vector_type(8)));
typedef float  f32x4  __attribute__((ext_vector_type(4)));

#define V_TOTAL 32768
#define VBLK    64
#define NT      256

#define LDS_H1  32768   // h1t: [64 pos][32 chunks of 16B], chunk slot = ks ^ (n&7)
#define LDS_A   16384   // per A buffer: 1024 chunks x 16B, linear (c = m*4 + kslot)

// async global->LDS, 16B per lane, LDS dest = wave-uniform base + lane*16
#define GLOAD_LDS16(g, l) __builtin_amdgcn_global_load_lds( \
    (const __attribute__((address_space(1))) void*)(g),     \
    (__attribute__((address_space(3))) void*)(l), 16, 0, 0)

// ---- prep: w2 fp32 -> bf16 (RNE) into workspace ----
__global__ void w2_to_bf16(const float* __restrict__ w2, __bf16* __restrict__ w2b) {
    int i = blockIdx.x * 256 + threadIdx.x;   // grid sized exactly: 8*256*256
    w2b[i] = (__bf16)w2[i];
}

__global__ __launch_bounds__(NT, 2) void fused_mlp(
    const float* __restrict__ x,  const int* __restrict__ obj,
    const float* __restrict__ w1, const float* __restrict__ b1,
    const float* __restrict__ b2, const float* __restrict__ w3,
    const float* __restrict__ b3, const __bf16* __restrict__ w2b,
    float* __restrict__ out)
{
    __shared__ __align__(16) char lds[LDS_H1 + 2 * LDS_A];   // 64 KiB
    char* h1t = lds;
    char* A0  = lds + LDS_H1;
    char* A1  = lds + LDS_H1 + LDS_A;
    float* w1s = (float*)A1;            // 6 KB, dead before A1 is first staged
    float* b1s = (float*)(A1 + 6144);   // 1 KB
    float* red = (float*)A0;            // 1 KB, used after K-loop (last tile in A1)

    const int t    = threadIdx.x;
    const int lane = t & 63;
    const int wv   = t >> 6;            // wave owns M rows [wv*64, wv*64+64)
    const int b    = blockIdx.x >> 9;   // 512 v-chunks per sample
    const int v0   = (blockIdx.x & 511) * VBLK;
    const int e    = obj[b];
    const __bf16* w2e = w2b + (size_t)e * 65536;

    // ---- issue W2 K-tile 0 into A0 (async), then stage w1/b1 ----
    #pragma unroll
    for (int i = 0; i < 4; ++i) {
        int cc = wv * 256 + i * 64 + lane;              // chunk = m*4 + kslot
        const __bf16* g = w2e + (cc >> 2) * 256 + (cc & 3) * 8;   // k0 = 0
        GLOAD_LDS16(g, A0 + (wv * 256 + i * 64) * 16);
    }
    for (int i = t; i < 1536; i += NT) w1s[i] = w1[e * 1536 + i];
    if (t < 256) b1s[t] = b1[e * 256 + t];
    __syncthreads();

    // ---- layer 1 (fp32 VALU): h1t[n][k] = relu(W1 x + b1), bf16, swizzled ----
    {
        float xr[6];
        #pragma unroll
        for (int i = 0; i < 6; ++i)
            xr[i] = x[(size_t)(b * 6 + i) * V_TOTAL + v0 + lane];
        char* drow = h1t + lane * 512;
        const int nx = lane & 7;
        #pragma unroll
        for (int q = 0; q < 8; ++q) {
            int m8 = wv * 8 + q;                        // 16B chunk index (8 h-vals)
            bf16x8 pack;
            #pragma unroll
            for (int j = 0; j < 8; ++j) {
                int m = m8 * 8 + j;
                float a = b1s[m];
                #pragma unroll
                for (int i2 = 0; i2 < 6; ++i2) a = fmaf(w1s[m * 6 + i2], xr[i2], a);
                pack[j] = (__bf16)fmaxf(a, 0.f);
            }
            *(bf16x8*)(drow + ((m8 ^ nx) << 4)) = pack;
        }
    }
    __syncthreads();   // h1 ready; tile 0 landed (barrier drains vmcnt)

    // ---- layer 2: M=256/K=256 GEMM, wave = 64 rows x 64 cols, dbuf A-tiles ----
    const int llo = lane & 15, lhi = lane >> 4;
    f32x4 acc[4][4];
    #pragma unroll
    for (int mt = 0; mt < 4; ++mt) {   // bias b2 per output row m
        f32x4 bv = *(const f32x4*)(b2 + e * 256 + wv * 64 + mt * 16 + lhi * 4);
        #pragma unroll
        for (int nt = 0; nt < 4; ++nt) acc[mt][nt] = bv;
    }

    for (int kt = 0; kt < 8; ++kt) {
        char* cur = (kt & 1) ? A1 : A0;
        char* nxt = (kt & 1) ? A0 : A1;
        if (kt < 7) {                              // prefetch next K-tile
            int k0n = (kt + 1) * 32;
            #pragma unroll
            for (int i = 0; i < 4; ++i) {
                int cc = wv * 256 + i * 64 + lane;
                const __bf16* g = w2e + (cc >> 2) * 256 + k0n + (cc & 3) * 8;
                GLOAD_LDS16(g, nxt + (wv * 256 + i * 64) * 16);
            }
        }
        bf16x8 aa[4], bb[4];
        const int kb = kt * 4;
        #pragma unroll
        for (int nt = 0; nt < 4; ++nt) {           // B: 2-way (free) via XOR swizzle
            int n = nt * 16 + llo;
            bb[nt] = *(const bf16x8*)(h1t + n * 512 + (((kb + lhi) ^ (n & 7)) << 4));
        }
        #pragma unroll
        for (int mt = 0; mt < 4; ++mt)             // A: 64 lanes contiguous 1KB, 0-way
            aa[mt] = *(const bf16x8*)(cur + (wv * 256 + mt * 64 + llo * 4 + lhi) * 16);
        #pragma unroll
        for (int mt = 0; mt < 4; ++mt)
            #pragma unroll
            for (int nt = 0; nt < 4; ++nt)
                acc[mt][nt] = __builtin_amdgcn_mfma_f32_16x16x32_bf16(
                    aa[mt], bb[nt], acc[mt][nt], 0, 0, 0);
        __syncthreads();   // drains next tile's vmcnt; cur safe to overwrite
    }

    // ---- layer 3: out[n] = sum_m w3[m]*relu(h2[m][n]) + b3, cross-wave reduce ----
    f32x4 wf[4];
    #pragma unroll
    for (int mt = 0; mt < 4; ++mt)
        wf[mt] = *(const f32x4*)(w3 + e * 256 + wv * 64 + mt * 16 + lhi * 4);
    float p[4];
    #pragma unroll
    for (int nt = 0; nt < 4; ++nt) {
        float s = 0.f;
        #pragma unroll
        for (int mt = 0; mt < 4; ++mt)
            #pragma unroll
            for (int j = 0; j < 4; ++j)
                s = fmaf(wf[mt][j], fmaxf(acc[mt][nt][j], 0.f), s);
        s += __shfl_xor(s, 16, 64);
        s += __shfl_xor(s, 32, 64);
        p[nt] = s;
    }
    if (lane < 16)
        #pragma unroll
        for (int nt = 0; nt < 4; ++nt)
            red[wv * 64 + nt * 16 + lane] = p[nt];
    __syncthreads();
    if (t < 64)
        out[(size_t)b * V_TOTAL + v0 + t] =
            red[t] + red[64 + t] + red[128 + t] + red[192 + t] + b3[e];
}

extern "C" void kernel_launch(void* const* d_in, const int* in_sizes, int n_in,
                              void* d_out, int out_size, void* d_ws, size_t ws_size,
                              hipStream_t stream) {
    const float* x   = (const float*)d_in[0];
    const int*   obj = (const int*)d_in[1];
    const float* w1  = (const float*)d_in[2];
    const float* b1  = (const float*)d_in[3];
    const float* w2  = (const float*)d_in[4];
    const float* b2  = (const float*)d_in[5];
    const float* w3  = (const float*)d_in[6];
    const float* b3  = (const float*)d_in[7];
    float*  out = (float*)d_out;
    __bf16* w2b = (__bf16*)d_ws;   // 8*256*256 bf16 = 1 MB

    w2_to_bf16<<<2048, 256, 0, stream>>>(w2, w2b);
    fused_mlp<<<8192, NT, 0, stream>>>(x, obj, w1, b1, b2, w3, b3, w2b, out);
}